// Round 17
// baseline (167.362 us; speedup 1.0000x reference)
//
#include <hip/hip_runtime.h>
#include <hip/hip_bf16.h>
#include <math.h>

#define B 64
#define O 64
#define F 1024
#define RN 16
#define RD 256
#define DEPTH 2
#define M (B*O)

typedef __attribute__((ext_vector_type(8))) _Float16 half8;
typedef __attribute__((ext_vector_type(4))) float f32x4;

#define RES_SCALE 2048.0f          // 2^11
#define RES_INV  (1.0f/2048.0f)

// ---------- fp16 split helpers: x = h + l*2^-11 (l stored pre-scaled) ----------
__device__ __forceinline__ unsigned short h2u(_Float16 h) {
  union { _Float16 h; unsigned short u; } c; c.h = h; return c.u;
}
__device__ __forceinline__ void split2(float x, unsigned short& h, unsigned short& l) {
  _Float16 hh = (_Float16)x;                       // RNE
  _Float16 ll = (_Float16)((x - (float)hh) * RES_SCALE);
  h = h2u(hh); l = h2u(ll);
}

__device__ __forceinline__ void gload_lds16(const unsigned short* g, void* l) {
  __builtin_amdgcn_global_load_lds(
      (const __attribute__((address_space(1))) unsigned int*)g,
      (__attribute__((address_space(3))) unsigned int*)l, 16, 0, 0);
}

// ------- merged prep 1: bid<4096 -> A reductions; else -> splitX --------------
__global__ __launch_bounds__(256) void k_prep(const float* __restrict__ A,
                                              const float* __restrict__ X,
                                              float* __restrict__ A1,
                                              float* __restrict__ A2,
                                              unsigned short* __restrict__ Xh,
                                              unsigned short* __restrict__ Xl) {
  __shared__ float row[O * RN];
  const int t = threadIdx.x;
  if (blockIdx.x < 4096) {
    const int bo = blockIdx.x;
    *reinterpret_cast<float4*>(&row[t * 4]) =
        *reinterpret_cast<const float4*>(&A[(size_t)bo * (O * RN) + t * 4]);
    __syncthreads();
    if (t < O) {
      float s = 0.f;
#pragma unroll
      for (int r = 0; r < RN; ++r) s += row[t * RN + r];
      A1[(size_t)bo * O + t] = s;
    } else if (t < O + RN) {
      const int r = t - O;
      float s = 0.f;
#pragma unroll
      for (int o2 = 0; o2 < O; ++o2) s += row[o2 * RN + r];
      A2[(size_t)bo * RN + r] = s;
    }
  } else {
    const size_t i = ((size_t)(blockIdx.x - 4096) * 256 + t) * 4;
    const float4 v = *reinterpret_cast<const float4*>(&X[i]);
    unsigned short h0, h1, h2, h3, l0, l1, l2, l3;
    split2(v.x, h0, l0); split2(v.y, h1, l1); split2(v.z, h2, l2); split2(v.w, h3, l3);
    uint2 hp, lp;
    hp.x = (unsigned)h0 | ((unsigned)h1 << 16); hp.y = (unsigned)h2 | ((unsigned)h3 << 16);
    lp.x = (unsigned)l0 | ((unsigned)l1 << 16); lp.y = (unsigned)l2 | ((unsigned)l3 << 16);
    *reinterpret_cast<uint2*>(&Xh[i]) = hp;
    *reinterpret_cast<uint2*>(&Xl[i]) = lp;
  }
}

// ------- merged prep 2: bid<4096 -> splitW both layers; else -> xrr -----------
__global__ __launch_bounds__(256) void k_prepW(const float* __restrict__ Wself,
                                               const float* __restrict__ Wrel,
                                               const float* __restrict__ brel,
                                               const float* __restrict__ R,
                                               unsigned short* __restrict__ Wht,
                                               unsigned short* __restrict__ Wlt,
                                               float* __restrict__ xrr) {
  __shared__ float T[32][33];
  const int t = threadIdx.x;
  const int bid = blockIdx.x;
  if (bid < 4096) {
    const int z = bid >> 10;                 // layer*2 + sel
    const int rem = bid & 1023;
    const int k0 = (rem & 31) * 32, n0 = (rem >> 5) * 32;
    const int layer = z >> 1;
    const int sel = z & 1;
    const float* W = sel ? (Wrel + (size_t)layer * (F + RD) * F)
                         : (Wself + (size_t)layer * F * F);
    const size_t obase = (size_t)layer * 2048 * 1024 + (size_t)(sel ? 1024 : 0) * 1024;
    const int r = t >> 3, c4 = (t & 7) << 2;
    const float4 v = *reinterpret_cast<const float4*>(&W[(size_t)(k0 + r) * 1024 + n0 + c4]);
    T[r][c4] = v.x; T[r][c4 + 1] = v.y; T[r][c4 + 2] = v.z; T[r][c4 + 3] = v.w;
    __syncthreads();
    unsigned short h[4], l[4];
#pragma unroll
    for (int j = 0; j < 4; ++j) split2(T[c4 + j][r], h[j], l[j]);
    uint2 hp, lp;
    hp.x = (unsigned)h[0] | ((unsigned)h[1] << 16); hp.y = (unsigned)h[2] | ((unsigned)h[3] << 16);
    lp.x = (unsigned)l[0] | ((unsigned)l[1] << 16); lp.y = (unsigned)l[2] | ((unsigned)l[3] << 16);
    const size_t o = obase + (size_t)(n0 + r) * 1024 + k0 + c4;
    *reinterpret_cast<uint2*>(&Wht[o]) = hp;
    *reinterpret_cast<uint2*>(&Wlt[o]) = lp;
  } else {
    const int r4 = bid - 4096;               // 0..127
    const int layer = r4 >> 6;
    const int idx = r4 & 63;
    const float* Wr = Wrel + (size_t)layer * (F + RD) * F + (size_t)F * F;
    const float* br = brel + (size_t)layer * F;
    const int r = idx >> 2;
    const int n = ((idx & 3) << 8) + t;
    float s = br[n];
    for (int k = 0; k < RD; ++k) s += R[r * RD + k] * Wr[(size_t)k * F + n];
    xrr[(size_t)layer * RN * F + (size_t)r * F + n] = s;
  }
}

// ---------------- staging + compute helpers (8-wave block, BK=64) ------------
// R11-proven: 32 chunks of 1KB (8 rows x 128B); wave w stages 4 chunks.
__device__ __forceinline__ void stage_tiles8(const unsigned short* __restrict__ Asrc,
                                             const unsigned short* __restrict__ Bsrc,
                                             int bm, int bn, int k0,
                                             int w, int lane,
                                             char* Al, char* Bl) {
  const int srow = lane >> 3;
  const int sin = (lane & 7) << 4;
#pragma unroll
  for (int i = 0; i < 4; ++i) {
    const int c = (w << 2) + i;          // 0..31, wave-uniform
    const int cc = c & 15;
    const int row = (cc << 3) + srow;
    const int inrow = sin ^ ((row & 7) << 4);   // pre-swizzled SOURCE byte
    const unsigned short* src = (c < 16) ? Asrc : Bsrc;
    const int rbase = (c < 16) ? bm : bn;
    char* ldst = (c < 16) ? Al : Bl;
    gload_lds16(src + ((size_t)(rbase + row) << 10) + k0 + (inrow >> 1), ldst + (cc << 10));
  }
}

// per-wave 64x32 output: 4 m-frags x 2 n-frags
__device__ __forceinline__ void compute_tile8(const char* Al, const char* Bl,
                                              int ar, int br, int kbyte,
                                              f32x4 (&acc)[4][2]) {
#pragma unroll
  for (int kk = 0; kk < 2; ++kk) {
    half8 a[4], b[2];
#pragma unroll
    for (int m = 0; m < 4; ++m) {
      const int row = ar + m * 16;
      const int off = (row << 7) + (((kk << 6) + kbyte) ^ ((row & 7) << 4));
      a[m] = *reinterpret_cast<const half8*>(&Al[off]);
    }
#pragma unroll
    for (int n = 0; n < 2; ++n) {
      const int row = br + n * 16;
      const int off = (row << 7) + (((kk << 6) + kbyte) ^ ((row & 7) << 4));
      b[n] = *reinterpret_cast<const half8*>(&Bl[off]);
    }
#pragma unroll
    for (int m = 0; m < 4; ++m)
#pragma unroll
      for (int n = 0; n < 2; ++n)
        acc[m][n] = __builtin_amdgcn_mfma_f32_16x16x32_f16(a[m], b[n], acc[m][n], 0, 0, 0);
  }
}

// 16-kt inner loop (K=1024), double-buffered with COUNTED vmcnt (T4):
//   stage(kt+1 -> buf^1); vmcnt(4) [only buf's loads]; s_barrier;
//   sched_barrier(0); compute(buf); s_barrier (WAR).
// The 4 prefetch loads stay in flight ACROSS the barrier and hide under MFMA.
// Buffer parity static via full unroll; vmcnt immediate folds at compile time.
__device__ __forceinline__ void gemm_piece8(const unsigned short* __restrict__ Asrc,
                                            const unsigned short* __restrict__ Bsrc,
                                            int bm, int bn, int w, int lane,
                                            int ar, int br, int kbyte,
                                            char* Al0, char* Bl0,
                                            char* Al1, char* Bl1,
                                            f32x4 (&acc)[4][2]) {
  stage_tiles8(Asrc, Bsrc, bm, bn, 0, w, lane, Al0, Bl0);
#pragma unroll
  for (int kt = 0; kt < 16; ++kt) {
    char* Ac = (kt & 1) ? Al1 : Al0;
    char* Bc = (kt & 1) ? Bl1 : Bl0;
    char* An = (kt & 1) ? Al0 : Al1;
    char* Bn = (kt & 1) ? Bl0 : Bl1;
    if (kt + 1 < 16) {
      stage_tiles8(Asrc, Bsrc, bm, bn, (kt + 1) << 6, w, lane, An, Bn);
      asm volatile("s_waitcnt vmcnt(4)" ::: "memory");  // wait current buf only
    } else {
      asm volatile("s_waitcnt vmcnt(0)" ::: "memory");  // last: full drain
    }
    __builtin_amdgcn_s_barrier();          // all waves: buf ready
    __builtin_amdgcn_sched_barrier(0);     // rule 18: pin reads after waitcnt
    compute_tile8(Ac, Bc, ar, br, kbyte, acc);
    __builtin_amdgcn_s_barrier();          // WAR: buf free to overwrite
  }
}

// ------- layer-1 fused MFMA GEMM ----------------------------------------------
// xrx half (bn>=1024): C = Xh@Wh + 2^-11*(Xh@Wl_st + Xl_st@Wh), K=3072.
// xs  half (bn< 1024): same (xs_full=1 for layer 1).
__global__ __launch_bounds__(512) void k_gemm_mfma(
    const unsigned short* __restrict__ Xh, const unsigned short* __restrict__ Xl,
    const unsigned short* __restrict__ Wht, const unsigned short* __restrict__ Wlt,
    float* __restrict__ xs, float* __restrict__ xrx, int xs_full) {
  __shared__ __align__(16) char Al0[128 * 128];
  __shared__ __align__(16) char Bl0[128 * 128];
  __shared__ __align__(16) char Al1[128 * 128];
  __shared__ __align__(16) char Bl1[128 * 128];
  const int t = threadIdx.x;
  const int lane = t & 63, w = t >> 6;
  const int bid = blockIdx.x;
  const int half = bid & 1;                 // 0 -> xrx (long), 1 -> xs
  int e = bid >> 1;
  e = (e & 7) * 32 + (e >> 3);               // XCD swizzle, bijective on 256
  const int bm = (e & 31) * 128;
  const int bn = (e >> 5) * 128 + (half ? 0 : 1024);
  const int wr = w >> 2, wc = w & 3;
  const bool full = (half == 0) || xs_full;

  f32x4 accM[4][2], accR[4][2];
#pragma unroll
  for (int m = 0; m < 4; ++m)
#pragma unroll
    for (int n = 0; n < 2; ++n) { accM[m][n] = (f32x4)0.f; accR[m][n] = (f32x4)0.f; }

  const int ar = wr * 64 + (lane & 15);
  const int br = wc * 32 + (lane & 15);
  const int kbyte = (lane >> 4) << 4;

  gemm_piece8(Xh, Wht, bm, bn, w, lane, ar, br, kbyte, Al0, Bl0, Al1, Bl1, accM);
  if (full) {
    gemm_piece8(Xh, Wlt, bm, bn, w, lane, ar, br, kbyte, Al0, Bl0, Al1, Bl1, accR);
    gemm_piece8(Xl, Wht, bm, bn, w, lane, ar, br, kbyte, Al0, Bl0, Al1, Bl1, accR);
  }

  float* dst = (bn < 1024) ? xs : xrx;
  const int coff = bn & 1023;
  const int lrow = (lane >> 4) << 2;
  const int lcol = lane & 15;
#pragma unroll
  for (int m = 0; m < 4; ++m)
#pragma unroll
    for (int n = 0; n < 2; ++n) {
      const int gr = bm + wr * 64 + m * 16 + lrow;
      const int gc = coff + wc * 32 + n * 16 + lcol;
#pragma unroll
      for (int i = 0; i < 4; ++i)
        dst[((size_t)(gr + i) << 10) + gc] = accM[m][n][i] + accR[m][n][i] * RES_INV;
    }
}

// ------- layer-2 GEMM: uniform 16-step blocks, 4 roles per tile-index ---------
// role 0: xs  = Xh@Wh (cols 0..1023)       role 1: xrx = Xh@Wh (cols 1024..)
// role 2: P1  = Xh@Wl_st (raw)             role 3: P2  = Xl_st@Wh (raw)
// consumer: xrx_eff = xrx + (P1+P2)*2^-11; xs needs no residual (last layer).
__global__ __launch_bounds__(512) void k_gemm_l2(
    const unsigned short* __restrict__ Xh, const unsigned short* __restrict__ Xl,
    const unsigned short* __restrict__ Wht, const unsigned short* __restrict__ Wlt,
    float* __restrict__ xs, float* __restrict__ xrx,
    float* __restrict__ P1, float* __restrict__ P2) {
  __shared__ __align__(16) char Al0[128 * 128];
  __shared__ __align__(16) char Bl0[128 * 128];
  __shared__ __align__(16) char Al1[128 * 128];
  __shared__ __align__(16) char Bl1[128 * 128];
  const int t = threadIdx.x;
  const int lane = t & 63, w = t >> 6;
  const int bid = blockIdx.x;
  const int role = bid & 3;
  int e = bid >> 2;
  e = (e & 7) * 32 + (e >> 3);               // XCD swizzle, bijective on 256
  const int bm = (e & 31) * 128;
  const int colblk = (e >> 5) * 128;
  const int bn = (role == 0) ? colblk : 1024 + colblk;
  const unsigned short* Asrc = (role == 3) ? Xl : Xh;
  const unsigned short* Bsrc = (role == 2) ? Wlt : Wht;
  float* dst = (role == 0) ? xs : (role == 1) ? xrx : (role == 2) ? P1 : P2;
  const int wr = w >> 2, wc = w & 3;

  f32x4 acc[4][2];
#pragma unroll
  for (int m = 0; m < 4; ++m)
#pragma unroll
    for (int n = 0; n < 2; ++n) acc[m][n] = (f32x4)0.f;

  const int ar = wr * 64 + (lane & 15);
  const int br = wc * 32 + (lane & 15);
  const int kbyte = (lane >> 4) << 4;

  gemm_piece8(Asrc, Bsrc, bm, bn, w, lane, ar, br, kbyte, Al0, Bl0, Al1, Bl1, acc);

  const int lrow = (lane >> 4) << 2;
  const int lcol = lane & 15;
#pragma unroll
  for (int m = 0; m < 4; ++m)
#pragma unroll
    for (int n = 0; n < 2; ++n) {
      const int gr = bm + wr * 64 + m * 16 + lrow;
      const int gc = colblk + wc * 32 + n * 16 + lcol;
#pragma unroll
      for (int i = 0; i < 4; ++i)
        dst[((size_t)(gr + i) << 10) + gc] = acc[m][n][i];
    }
}

// ------- out = tanh(xs + bself + A1[b]@xr_x[b] + A2[b]@xr_r + x_in) ----------
// use_p: xr_x = xrx + (P1+P2)*2^-11 (layer 2); else xr_x = xrx (layer 1).
__global__ __launch_bounds__(256) void k_agg(const float* __restrict__ A1,
                                             const float* __restrict__ A2,
                                             const float* __restrict__ xrx,
                                             const float* __restrict__ P1,
                                             const float* __restrict__ P2,
                                             const float* __restrict__ xrr,
                                             const float* __restrict__ xs,
                                             const float* __restrict__ bias,
                                             const float* __restrict__ xin,
                                             float* __restrict__ xout,
                                             unsigned short* __restrict__ XhO,
                                             unsigned short* __restrict__ XlO,
                                             int use_p) {
  __shared__ float A1s[O][O + 1];
  __shared__ float A2s[O][RN + 1];
  __shared__ float Xls[O][132];
  __shared__ float Rls[RN][132];
  const int b = blockIdx.x;
  const int f0 = blockIdx.y * 128;
  const int t = threadIdx.x;

#pragma unroll
  for (int i = 0; i < 4; ++i) {
    const int gi = i * 1024 + t * 4;
    const float4 v = *reinterpret_cast<const float4*>(&A1[(size_t)b * O * O + gi]);
    const int o = gi >> 6, c = gi & 63;
    A1s[o][c] = v.x; A1s[o][c + 1] = v.y; A1s[o][c + 2] = v.z; A1s[o][c + 3] = v.w;
  }
  {
    const int gi = t * 4;
    const float4 v = *reinterpret_cast<const float4*>(&A2[(size_t)b * O * RN + gi]);
    const int o = gi >> 4, c = gi & 15;
    A2s[o][c] = v.x; A2s[o][c + 1] = v.y; A2s[o][c + 2] = v.z; A2s[o][c + 3] = v.w;
  }
#pragma unroll
  for (int i = 0; i < 8; ++i) {
    const int gi = i * 1024 + t * 4;
    const int o2 = gi >> 7, c = gi & 127;
    const size_t pidx = ((size_t)(b * O + o2)) * F + f0 + c;
    float4 v = *reinterpret_cast<const float4*>(&xrx[pidx]);
    if (use_p) {
      const float4 p1 = *reinterpret_cast<const float4*>(&P1[pidx]);
      const float4 p2 = *reinterpret_cast<const float4*>(&P2[pidx]);
      v.x += (p1.x + p2.x) * RES_INV; v.y += (p1.y + p2.y) * RES_INV;
      v.z += (p1.z + p2.z) * RES_INV; v.w += (p1.w + p2.w) * RES_INV;
    }
    Xls[o2][c] = v.x; Xls[o2][c + 1] = v.y; Xls[o2][c + 2] = v.z; Xls[o2][c + 3] = v.w;
  }
#pragma unroll
  for (int i = 0; i < 2; ++i) {
    const int gi = i * 1024 + t * 4;
    const int r = gi >> 7, c = gi & 127;
    const float4 v = *reinterpret_cast<const float4*>(&xrr[(size_t)r * F + f0 + c]);
    Rls[r][c] = v.x; Rls[r][c + 1] = v.y; Rls[r][c + 2] = v.z; Rls[r][c + 3] = v.w;
  }
  __syncthreads();

  const int ob = (t >> 4) << 2;
  const int fc = (t & 15) << 2;
  float acc[4][8];
#pragma unroll
  for (int i = 0; i < 4; ++i)
#pragma unroll
    for (int j = 0; j < 8; ++j) acc[i][j] = 0.f;

#pragma unroll 4
  for (int o2 = 0; o2 < O; ++o2) {
    const float4 xa = *reinterpret_cast<const float4*>(&Xls[o2][fc]);
    const float4 xb = *reinterpret_cast<const float4*>(&Xls[o2][fc + 64]);
#pragma unroll
    for (int io = 0; io < 4; ++io) {
      const float a = A1s[ob + io][o2];
      acc[io][0] += a * xa.x; acc[io][1] += a * xa.y; acc[io][2] += a * xa.z; acc[io][3] += a * xa.w;
      acc[io][4] += a * xb.x; acc[io][5] += a * xb.y; acc[io][6] += a * xb.z; acc[io][7] += a * xb.w;
    }
  }
#pragma unroll
  for (int r = 0; r < RN; ++r) {
    const float4 xa = *reinterpret_cast<const float4*>(&Rls[r][fc]);
    const float4 xb = *reinterpret_cast<const float4*>(&Rls[r][fc + 64]);
#pragma unroll
    for (int io = 0; io < 4; ++io) {
      const float a = A2s[ob + io][r];
      acc[io][0] += a * xa.x; acc[io][1] += a * xa.y; acc[io][2] += a * xa.z; acc[io][3] += a * xa.w;
      acc[io][4] += a * xb.x; acc[io][5] += a * xb.y; acc[io][6] += a * xb.z; acc[io][7] += a * xb.w;
    }
  }

#pragma unroll
  for (int io = 0; io < 4; ++io) {
    const size_t base = ((size_t)(b * O + ob + io)) * F + f0;
#pragma unroll
    for (int seg = 0; seg < 2; ++seg) {
      const size_t idx = base + seg * 64 + fc;
      const float4 s = *reinterpret_cast<const float4*>(&xs[idx]);
      const float4 bv = *reinterpret_cast<const float4*>(&bias[f0 + seg * 64 + fc]);
      const float4 xi = *reinterpret_cast<const float4*>(&xin[idx]);
      float4 o;
      o.x = tanhf(acc[io][seg * 4 + 0] + s.x + bv.x + xi.x);
      o.y = tanhf(acc[io][seg * 4 + 1] + s.y + bv.y + xi.y);
      o.z = tanhf(acc[io][seg * 4 + 2] + s.z + bv.z + xi.z);
      o.w = tanhf(acc[io][seg * 4 + 3] + s.w + bv.w + xi.w);
      *reinterpret_cast<float4*>(&xout[idx]) = o;
      if (XhO) {
        unsigned short h0, h1, h2, h3, l0, l1, l2, l3;
        split2(o.x, h0, l0); split2(o.y, h1, l1); split2(o.z, h2, l2); split2(o.w, h3, l3);
        uint2 hp, lp;
        hp.x = (unsigned)h0 | ((unsigned)h1 << 16); hp.y = (unsigned)h2 | ((unsigned)h3 << 16);
        lp.x = (unsigned)l0 | ((unsigned)l1 << 16); lp.y = (unsigned)l2 | ((unsigned)l3 << 16);
        *reinterpret_cast<uint2*>(&XhO[idx]) = hp;
        *reinterpret_cast<uint2*>(&XlO[idx]) = lp;
      }
    }
  }
}

extern "C" void kernel_launch(void* const* d_in, const int* in_sizes, int n_in,
                              void* d_out, int out_size, void* d_ws, size_t ws_size,
                              hipStream_t stream) {
  const float* x0    = (const float*)d_in[0];
  const float* A     = (const float*)d_in[1];
  const float* R     = (const float*)d_in[2];
  const float* Wself = (const float*)d_in[3];
  const float* bself = (const float*)d_in[4];
  const float* Wrel  = (const float*)d_in[5];
  const float* brel  = (const float*)d_in[6];
  float* out = (float*)d_out;

  float* ws  = (float*)d_ws;
  float* A1  = ws;                               // 1 MB
  float* A2  = A1 + (size_t)M * O;               // 0.25 MB
  float* xrr = A2 + (size_t)M * RN;              // 2 layers x RN x F
  float* xs  = xrr + (size_t)2 * RN * F;         // 16 MB
  float* xrx = xs + (size_t)M * F;               // 16 MB
  float* P1  = xrx + (size_t)M * F;              // 16 MB
  float* P2  = P1 + (size_t)M * F;               // 16 MB
  unsigned short* Xh  = (unsigned short*)(P2 + (size_t)M * F);     // 8 MB
  unsigned short* Xl  = Xh + (size_t)M * F;                        // 8 MB
  unsigned short* Wht = Xl + (size_t)M * F;      // 2 layers x [2048][1024] = 8 MB
  unsigned short* Wlt = Wht + (size_t)2 * 2048 * 1024;             // 8 MB
  // total ws use ~97 MB

  k_prep<<<8192, 256, 0, stream>>>(A, x0, A1, A2, Xh, Xl);
  k_prepW<<<4096 + 128, 256, 0, stream>>>(Wself, Wrel, brel, R, Wht, Wlt, xrr);

  // ---- layer 1 ----
  k_gemm_mfma<<<512, 512, 0, stream>>>(Xh, Xl, Wht, Wlt, xs, xrx, 1);
  k_agg<<<dim3(B, F / 128), 256, 0, stream>>>(A1, A2, xrx, P1, P2,
                                              xrr, xs, bself, x0, out,
                                              Xh, Xl, 0);
  // ---- layer 2 ----
  k_gemm_l2<<<1024, 512, 0, stream>>>(Xh, Xl,
                                      Wht + (size_t)2048 * 1024,
                                      Wlt + (size_t)2048 * 1024,
                                      xs, xrx, P1, P2);
  k_agg<<<dim3(B, F / 128), 256, 0, stream>>>(A1, A2, xrx, P1, P2,
                                              xrr + (size_t)RN * F, xs,
                                              bself + (size_t)F, out, out,
                                              nullptr, nullptr, 1);
}

// Round 18
// 161.888 us; speedup vs baseline: 1.0338x; 1.0338x over previous
//
#include <hip/hip_runtime.h>
#include <hip/hip_bf16.h>
#include <math.h>

#define B 64
#define O 64
#define F 1024
#define RN 16
#define RD 256
#define DEPTH 2
#define M (B*O)

typedef __attribute__((ext_vector_type(8))) _Float16 half8;
typedef __attribute__((ext_vector_type(4))) float f32x4;

#define RES_SCALE 2048.0f          // 2^11
#define RES_INV  (1.0f/2048.0f)

// ---------- fp16 helpers ----------
__device__ __forceinline__ unsigned short h2u(_Float16 h) {
  union { _Float16 h; unsigned short u; } c; c.h = h; return c.u;
}
__device__ __forceinline__ float u2f(unsigned short u) {
  union { _Float16 h; unsigned short u; } c; c.u = u; return (float)c.h;
}
__device__ __forceinline__ void split2(float x, unsigned short& h, unsigned short& l) {
  _Float16 hh = (_Float16)x;                       // RNE
  _Float16 ll = (_Float16)((x - (float)hh) * RES_SCALE);
  h = h2u(hh); l = h2u(ll);
}

__device__ __forceinline__ void gload_lds16(const unsigned short* g, void* l) {
  __builtin_amdgcn_global_load_lds(
      (const __attribute__((address_space(1))) unsigned int*)g,
      (__attribute__((address_space(3))) unsigned int*)l, 16, 0, 0);
}

// ------- merged prep: [0,4096) A-reduce; [4096,8192) splitX;
//         [8192,12288) splitW both layers; [12288,12416) xrr ------------------
__global__ __launch_bounds__(256) void k_prepAll(const float* __restrict__ A,
                                                 const float* __restrict__ X,
                                                 const float* __restrict__ Wself,
                                                 const float* __restrict__ Wrel,
                                                 const float* __restrict__ brel,
                                                 const float* __restrict__ R,
                                                 float* __restrict__ A1,
                                                 float* __restrict__ A2,
                                                 unsigned short* __restrict__ Xh,
                                                 unsigned short* __restrict__ Xl,
                                                 unsigned short* __restrict__ Wht,
                                                 unsigned short* __restrict__ Wlt,
                                                 float* __restrict__ xrr) {
  __shared__ float shm[32][33];
  const int t = threadIdx.x;
  const int bid = blockIdx.x;
  if (bid < 4096) {
    float* row = &shm[0][0];                 // 1056 floats > 1024 needed
    const int bo = bid;
    *reinterpret_cast<float4*>(&row[t * 4]) =
        *reinterpret_cast<const float4*>(&A[(size_t)bo * (O * RN) + t * 4]);
    __syncthreads();
    if (t < O) {
      float s = 0.f;
#pragma unroll
      for (int r = 0; r < RN; ++r) s += row[t * RN + r];
      A1[(size_t)bo * O + t] = s;
    } else if (t < O + RN) {
      const int r = t - O;
      float s = 0.f;
#pragma unroll
      for (int o2 = 0; o2 < O; ++o2) s += row[o2 * RN + r];
      A2[(size_t)bo * RN + r] = s;
    }
  } else if (bid < 8192) {
    const size_t i = ((size_t)(bid - 4096) * 256 + t) * 4;
    const float4 v = *reinterpret_cast<const float4*>(&X[i]);
    unsigned short h0, h1, h2, h3, l0, l1, l2, l3;
    split2(v.x, h0, l0); split2(v.y, h1, l1); split2(v.z, h2, l2); split2(v.w, h3, l3);
    uint2 hp, lp;
    hp.x = (unsigned)h0 | ((unsigned)h1 << 16); hp.y = (unsigned)h2 | ((unsigned)h3 << 16);
    lp.x = (unsigned)l0 | ((unsigned)l1 << 16); lp.y = (unsigned)l2 | ((unsigned)l3 << 16);
    *reinterpret_cast<uint2*>(&Xh[i]) = hp;
    *reinterpret_cast<uint2*>(&Xl[i]) = lp;
  } else if (bid < 12288) {
    const int wb = bid - 8192;
    const int z = wb >> 10;                  // layer*2 + sel
    const int rem = wb & 1023;
    const int k0 = (rem & 31) * 32, n0 = (rem >> 5) * 32;
    const int layer = z >> 1;
    const int sel = z & 1;
    const float* W = sel ? (Wrel + (size_t)layer * (F + RD) * F)
                         : (Wself + (size_t)layer * F * F);
    const size_t obase = (size_t)layer * 2048 * 1024 + (size_t)(sel ? 1024 : 0) * 1024;
    const int r = t >> 3, c4 = (t & 7) << 2;
    const float4 v = *reinterpret_cast<const float4*>(&W[(size_t)(k0 + r) * 1024 + n0 + c4]);
    shm[r][c4] = v.x; shm[r][c4 + 1] = v.y; shm[r][c4 + 2] = v.z; shm[r][c4 + 3] = v.w;
    __syncthreads();
    unsigned short h[4], l[4];
#pragma unroll
    for (int j = 0; j < 4; ++j) split2(shm[c4 + j][r], h[j], l[j]);
    uint2 hp, lp;
    hp.x = (unsigned)h[0] | ((unsigned)h[1] << 16); hp.y = (unsigned)h[2] | ((unsigned)h[3] << 16);
    lp.x = (unsigned)l[0] | ((unsigned)l[1] << 16); lp.y = (unsigned)l[2] | ((unsigned)l[3] << 16);
    const size_t o = obase + (size_t)(n0 + r) * 1024 + k0 + c4;
    *reinterpret_cast<uint2*>(&Wht[o]) = hp;
    *reinterpret_cast<uint2*>(&Wlt[o]) = lp;
  } else {
    const int r4 = bid - 12288;              // 0..127
    const int layer = r4 >> 6;
    const int idx = r4 & 63;
    const float* Wr = Wrel + (size_t)layer * (F + RD) * F + (size_t)F * F;
    const float* br = brel + (size_t)layer * F;
    const int r = idx >> 2;
    const int n = ((idx & 3) << 8) + t;
    float s = br[n];
    for (int k = 0; k < RD; ++k) s += R[r * RD + k] * Wr[(size_t)k * F + n];
    xrr[(size_t)layer * RN * F + (size_t)r * F + n] = s;
  }
}

// ---------------- staging + compute helpers (8-wave block, BK=64) ------------
__device__ __forceinline__ void stage_tiles8(const unsigned short* __restrict__ Asrc,
                                             const unsigned short* __restrict__ Bsrc,
                                             int bm, int bn, int k0,
                                             int w, int lane,
                                             char* Al, char* Bl) {
  const int srow = lane >> 3;
  const int sin = (lane & 7) << 4;
#pragma unroll
  for (int i = 0; i < 4; ++i) {
    const int c = (w << 2) + i;          // 0..31, wave-uniform
    const int cc = c & 15;
    const int row = (cc << 3) + srow;
    const int inrow = sin ^ ((row & 7) << 4);   // pre-swizzled SOURCE byte
    const unsigned short* src = (c < 16) ? Asrc : Bsrc;
    const int rbase = (c < 16) ? bm : bn;
    char* ldst = (c < 16) ? Al : Bl;
    gload_lds16(src + ((size_t)(rbase + row) << 10) + k0 + (inrow >> 1), ldst + (cc << 10));
  }
}

// per-wave 64x32 output: 4 m-frags x 2 n-frags; T5 setprio around MFMA cluster
__device__ __forceinline__ void compute_tile8(const char* Al, const char* Bl,
                                              int ar, int br, int kbyte,
                                              f32x4 (&acc)[4][2]) {
  __builtin_amdgcn_s_setprio(1);
#pragma unroll
  for (int kk = 0; kk < 2; ++kk) {
    half8 a[4], b[2];
#pragma unroll
    for (int m = 0; m < 4; ++m) {
      const int row = ar + m * 16;
      const int off = (row << 7) + (((kk << 6) + kbyte) ^ ((row & 7) << 4));
      a[m] = *reinterpret_cast<const half8*>(&Al[off]);
    }
#pragma unroll
    for (int n = 0; n < 2; ++n) {
      const int row = br + n * 16;
      const int off = (row << 7) + (((kk << 6) + kbyte) ^ ((row & 7) << 4));
      b[n] = *reinterpret_cast<const half8*>(&Bl[off]);
    }
#pragma unroll
    for (int m = 0; m < 4; ++m)
#pragma unroll
      for (int n = 0; n < 2; ++n)
        acc[m][n] = __builtin_amdgcn_mfma_f32_16x16x32_f16(a[m], b[n], acc[m][n], 0, 0, 0);
  }
  __builtin_amdgcn_s_setprio(0);
}

// 16-kt inner loop (K=1024), DOUBLE-BUFFERED single-barrier 2-phase (R16-proven):
// prologue stage(0->buf0); loop { stage(kt+1 -> buf^1); compute(buf); sync; }.
__device__ __forceinline__ void gemm_piece8(const unsigned short* __restrict__ Asrc,
                                            const unsigned short* __restrict__ Bsrc,
                                            int bm, int bn, int w, int lane,
                                            int ar, int br, int kbyte,
                                            char* Al0, char* Bl0,
                                            char* Al1, char* Bl1,
                                            f32x4 (&acc)[4][2]) {
  stage_tiles8(Asrc, Bsrc, bm, bn, 0, w, lane, Al0, Bl0);
  __syncthreads();
#pragma unroll
  for (int kt = 0; kt < 16; ++kt) {
    char* Ac = (kt & 1) ? Al1 : Al0;
    char* Bc = (kt & 1) ? Bl1 : Bl0;
    char* An = (kt & 1) ? Al0 : Al1;
    char* Bn = (kt & 1) ? Bl0 : Bl1;
    if (kt + 1 < 16)
      stage_tiles8(Asrc, Bsrc, bm, bn, (kt + 1) << 6, w, lane, An, Bn);
    compute_tile8(Ac, Bc, ar, br, kbyte, acc);
    __syncthreads();
  }
}

// ------- layer-1 fused MFMA GEMM ----------------------------------------------
// xrx half (bn>=1024): C = Xh@Wh + 2^-11*(Xh@Wl_st + Xl_st@Wh), K=3072.
// xs  half (bn< 1024): same (xs_full=1 for layer 1).
__global__ __launch_bounds__(512) void k_gemm_mfma(
    const unsigned short* __restrict__ Xh, const unsigned short* __restrict__ Xl,
    const unsigned short* __restrict__ Wht, const unsigned short* __restrict__ Wlt,
    float* __restrict__ xs, float* __restrict__ xrx, int xs_full) {
  __shared__ __align__(16) char Al0[128 * 128];
  __shared__ __align__(16) char Bl0[128 * 128];
  __shared__ __align__(16) char Al1[128 * 128];
  __shared__ __align__(16) char Bl1[128 * 128];
  const int t = threadIdx.x;
  const int lane = t & 63, w = t >> 6;
  const int bid = blockIdx.x;
  const int half = bid & 1;                 // 0 -> xrx (long), 1 -> xs
  int e = bid >> 1;
  e = (e & 7) * 32 + (e >> 3);               // XCD swizzle, bijective on 256
  const int bm = (e & 31) * 128;
  const int bn = (e >> 5) * 128 + (half ? 0 : 1024);
  const int wr = w >> 2, wc = w & 3;
  const bool full = (half == 0) || xs_full;

  f32x4 accM[4][2], accR[4][2];
#pragma unroll
  for (int m = 0; m < 4; ++m)
#pragma unroll
    for (int n = 0; n < 2; ++n) { accM[m][n] = (f32x4)0.f; accR[m][n] = (f32x4)0.f; }

  const int ar = wr * 64 + (lane & 15);
  const int br = wc * 32 + (lane & 15);
  const int kbyte = (lane >> 4) << 4;

  gemm_piece8(Xh, Wht, bm, bn, w, lane, ar, br, kbyte, Al0, Bl0, Al1, Bl1, accM);
  if (full) {
    gemm_piece8(Xh, Wlt, bm, bn, w, lane, ar, br, kbyte, Al0, Bl0, Al1, Bl1, accR);
    gemm_piece8(Xl, Wht, bm, bn, w, lane, ar, br, kbyte, Al0, Bl0, Al1, Bl1, accR);
  }

  float* dst = (bn < 1024) ? xs : xrx;
  const int coff = bn & 1023;
  const int lrow = (lane >> 4) << 2;
  const int lcol = lane & 15;
#pragma unroll
  for (int m = 0; m < 4; ++m)
#pragma unroll
    for (int n = 0; n < 2; ++n) {
      const int gr = bm + wr * 64 + m * 16 + lrow;
      const int gc = coff + wc * 32 + n * 16 + lcol;
#pragma unroll
      for (int i = 0; i < 4; ++i)
        dst[((size_t)(gr + i) << 10) + gc] = accM[m][n][i] + accR[m][n][i] * RES_INV;
    }
}

// ------- layer-2 GEMM: uniform 16-step blocks, 4 roles per tile-index ---------
// role 0: xs  = Xh@Wh (cols 0..1023)       role 1: xrx = Xh@Wh (cols 1024..)
// role 2: P1h = Xh@Wl_st (raw, fp16)       role 3: P2h = Xl_st@Wh (raw, fp16)
// consumer: xrx_eff = xrx + (P1+P2)*2^-11; xs needs no residual (last layer).
__global__ __launch_bounds__(512) void k_gemm_l2(
    const unsigned short* __restrict__ Xh, const unsigned short* __restrict__ Xl,
    const unsigned short* __restrict__ Wht, const unsigned short* __restrict__ Wlt,
    float* __restrict__ xs, float* __restrict__ xrx,
    unsigned short* __restrict__ P1h, unsigned short* __restrict__ P2h) {
  __shared__ __align__(16) char Al0[128 * 128];
  __shared__ __align__(16) char Bl0[128 * 128];
  __shared__ __align__(16) char Al1[128 * 128];
  __shared__ __align__(16) char Bl1[128 * 128];
  const int t = threadIdx.x;
  const int lane = t & 63, w = t >> 6;
  const int bid = blockIdx.x;
  const int role = bid & 3;
  int e = bid >> 2;
  e = (e & 7) * 32 + (e >> 3);               // XCD swizzle, bijective on 256
  const int bm = (e & 31) * 128;
  const int colblk = (e >> 5) * 128;
  const int bn = (role == 0) ? colblk : 1024 + colblk;
  const unsigned short* Asrc = (role == 3) ? Xl : Xh;
  const unsigned short* Bsrc = (role == 2) ? Wlt : Wht;
  const int wr = w >> 2, wc = w & 3;

  f32x4 acc[4][2];
#pragma unroll
  for (int m = 0; m < 4; ++m)
#pragma unroll
    for (int n = 0; n < 2; ++n) acc[m][n] = (f32x4)0.f;

  const int ar = wr * 64 + (lane & 15);
  const int br = wc * 32 + (lane & 15);
  const int kbyte = (lane >> 4) << 4;

  gemm_piece8(Asrc, Bsrc, bm, bn, w, lane, ar, br, kbyte, Al0, Bl0, Al1, Bl1, acc);

  const int lrow = (lane >> 4) << 2;
  const int lcol = lane & 15;
  if (role < 2) {
    float* dst = (role == 0) ? xs : xrx;
#pragma unroll
    for (int m = 0; m < 4; ++m)
#pragma unroll
      for (int n = 0; n < 2; ++n) {
        const int gr = bm + wr * 64 + m * 16 + lrow;
        const int gc = colblk + wc * 32 + n * 16 + lcol;
#pragma unroll
        for (int i = 0; i < 4; ++i)
          dst[((size_t)(gr + i) << 10) + gc] = acc[m][n][i];
      }
  } else {
    unsigned short* dst = (role == 2) ? P1h : P2h;
#pragma unroll
    for (int m = 0; m < 4; ++m)
#pragma unroll
      for (int n = 0; n < 2; ++n) {
        const int gr = bm + wr * 64 + m * 16 + lrow;
        const int gc = colblk + wc * 32 + n * 16 + lcol;
#pragma unroll
        for (int i = 0; i < 4; ++i)
          dst[((size_t)(gr + i) << 10) + gc] = h2u((_Float16)acc[m][n][i]);
      }
  }
}

// ------- out = tanh(xs + bself + A1[b]@xr_x[b] + A2[b]@xr_r + x_in) ----------
// use_p: xr_x = xrx + (P1h+P2h)*2^-11 (layer 2); else xr_x = xrx (layer 1).
__global__ __launch_bounds__(256) void k_agg(const float* __restrict__ A1,
                                             const float* __restrict__ A2,
                                             const float* __restrict__ xrx,
                                             const unsigned short* __restrict__ P1h,
                                             const unsigned short* __restrict__ P2h,
                                             const float* __restrict__ xrr,
                                             const float* __restrict__ xs,
                                             const float* __restrict__ bias,
                                             const float* __restrict__ xin,
                                             float* __restrict__ xout,
                                             unsigned short* __restrict__ XhO,
                                             unsigned short* __restrict__ XlO,
                                             int use_p) {
  __shared__ float A1s[O][O + 1];
  __shared__ float A2s[O][RN + 1];
  __shared__ float Xls[O][132];
  __shared__ float Rls[RN][132];
  const int b = blockIdx.x;
  const int f0 = blockIdx.y * 128;
  const int t = threadIdx.x;

#pragma unroll
  for (int i = 0; i < 4; ++i) {
    const int gi = i * 1024 + t * 4;
    const float4 v = *reinterpret_cast<const float4*>(&A1[(size_t)b * O * O + gi]);
    const int o = gi >> 6, c = gi & 63;
    A1s[o][c] = v.x; A1s[o][c + 1] = v.y; A1s[o][c + 2] = v.z; A1s[o][c + 3] = v.w;
  }
  {
    const int gi = t * 4;
    const float4 v = *reinterpret_cast<const float4*>(&A2[(size_t)b * O * RN + gi]);
    const int o = gi >> 4, c = gi & 15;
    A2s[o][c] = v.x; A2s[o][c + 1] = v.y; A2s[o][c + 2] = v.z; A2s[o][c + 3] = v.w;
  }
#pragma unroll
  for (int i = 0; i < 8; ++i) {
    const int gi = i * 1024 + t * 4;
    const int o2 = gi >> 7, c = gi & 127;
    const size_t pidx = ((size_t)(b * O + o2)) * F + f0 + c;
    float4 v = *reinterpret_cast<const float4*>(&xrx[pidx]);
    if (use_p) {
      const uint2 p1 = *reinterpret_cast<const uint2*>(&P1h[pidx]);
      const uint2 p2 = *reinterpret_cast<const uint2*>(&P2h[pidx]);
      v.x += (u2f((unsigned short)(p1.x & 0xffff)) + u2f((unsigned short)(p2.x & 0xffff))) * RES_INV;
      v.y += (u2f((unsigned short)(p1.x >> 16))    + u2f((unsigned short)(p2.x >> 16)))    * RES_INV;
      v.z += (u2f((unsigned short)(p1.y & 0xffff)) + u2f((unsigned short)(p2.y & 0xffff))) * RES_INV;
      v.w += (u2f((unsigned short)(p1.y >> 16))    + u2f((unsigned short)(p2.y >> 16)))    * RES_INV;
    }
    Xls[o2][c] = v.x; Xls[o2][c + 1] = v.y; Xls[o2][c + 2] = v.z; Xls[o2][c + 3] = v.w;
  }
#pragma unroll
  for (int i = 0; i < 2; ++i) {
    const int gi = i * 1024 + t * 4;
    const int r = gi >> 7, c = gi & 127;
    const float4 v = *reinterpret_cast<const float4*>(&xrr[(size_t)r * F + f0 + c]);
    Rls[r][c] = v.x; Rls[r][c + 1] = v.y; Rls[r][c + 2] = v.z; Rls[r][c + 3] = v.w;
  }
  __syncthreads();

  const int ob = (t >> 4) << 2;
  const int fc = (t & 15) << 2;
  float acc[4][8];
#pragma unroll
  for (int i = 0; i < 4; ++i)
#pragma unroll
    for (int j = 0; j < 8; ++j) acc[i][j] = 0.f;

#pragma unroll 4
  for (int o2 = 0; o2 < O; ++o2) {
    const float4 xa = *reinterpret_cast<const float4*>(&Xls[o2][fc]);
    const float4 xb = *reinterpret_cast<const float4*>(&Xls[o2][fc + 64]);
#pragma unroll
    for (int io = 0; io < 4; ++io) {
      const float a = A1s[ob + io][o2];
      acc[io][0] += a * xa.x; acc[io][1] += a * xa.y; acc[io][2] += a * xa.z; acc[io][3] += a * xa.w;
      acc[io][4] += a * xb.x; acc[io][5] += a * xb.y; acc[io][6] += a * xb.z; acc[io][7] += a * xb.w;
    }
  }
#pragma unroll
  for (int r = 0; r < RN; ++r) {
    const float4 xa = *reinterpret_cast<const float4*>(&Rls[r][fc]);
    const float4 xb = *reinterpret_cast<const float4*>(&Rls[r][fc + 64]);
#pragma unroll
    for (int io = 0; io < 4; ++io) {
      const float a = A2s[ob + io][r];
      acc[io][0] += a * xa.x; acc[io][1] += a * xa.y; acc[io][2] += a * xa.z; acc[io][3] += a * xa.w;
      acc[io][4] += a * xb.x; acc[io][5] += a * xb.y; acc[io][6] += a * xb.z; acc[io][7] += a * xb.w;
    }
  }

#pragma unroll
  for (int io = 0; io < 4; ++io) {
    const size_t base = ((size_t)(b * O + ob + io)) * F + f0;
#pragma unroll
    for (int seg = 0; seg < 2; ++seg) {
      const size_t idx = base + seg * 64 + fc;
      const float4 s = *reinterpret_cast<const float4*>(&xs[idx]);
      const float4 bv = *reinterpret_cast<const float4*>(&bias[f0 + seg * 64 + fc]);
      const float4 xi = *reinterpret_cast<const float4*>(&xin[idx]);
      float4 o;
      o.x = tanhf(acc[io][seg * 4 + 0] + s.x + bv.x + xi.x);
      o.y = tanhf(acc[io][seg * 4 + 1] + s.y + bv.y + xi.y);
      o.z = tanhf(acc[io][seg * 4 + 2] + s.z + bv.z + xi.z);
      o.w = tanhf(acc[io][seg * 4 + 3] + s.w + bv.w + xi.w);
      *reinterpret_cast<float4*>(&xout[idx]) = o;
      if (XhO) {
        unsigned short h0, h1, h2, h3, l0, l1, l2, l3;
        split2(o.x, h0, l0); split2(o.y, h1, l1); split2(o.z, h2, l2); split2(o.w, h3, l3);
        uint2 hp, lp;
        hp.x = (unsigned)h0 | ((unsigned)h1 << 16); hp.y = (unsigned)h2 | ((unsigned)h3 << 16);
        lp.x = (unsigned)l0 | ((unsigned)l1 << 16); lp.y = (unsigned)l2 | ((unsigned)l3 << 16);
        *reinterpret_cast<uint2*>(&XhO[idx]) = hp;
        *reinterpret_cast<uint2*>(&XlO[idx]) = lp;
      }
    }
  }
}

extern "C" void kernel_launch(void* const* d_in, const int* in_sizes, int n_in,
                              void* d_out, int out_size, void* d_ws, size_t ws_size,
                              hipStream_t stream) {
  const float* x0    = (const float*)d_in[0];
  const float* A     = (const float*)d_in[1];
  const float* R     = (const float*)d_in[2];
  const float* Wself = (const float*)d_in[3];
  const float* bself = (const float*)d_in[4];
  const float* Wrel  = (const float*)d_in[5];
  const float* brel  = (const float*)d_in[6];
  float* out = (float*)d_out;

  float* ws  = (float*)d_ws;
  float* A1  = ws;                               // 1 MB
  float* A2  = A1 + (size_t)M * O;               // 0.25 MB
  float* xrr = A2 + (size_t)M * RN;              // 2 layers x RN x F
  float* xs  = xrr + (size_t)2 * RN * F;         // 16 MB
  float* xrx = xs + (size_t)M * F;               // 16 MB
  unsigned short* P1h = (unsigned short*)(xrx + (size_t)M * F);    // 8 MB
  unsigned short* P2h = P1h + (size_t)M * F;                       // 8 MB
  unsigned short* Xh  = P2h + (size_t)M * F;                       // 8 MB
  unsigned short* Xl  = Xh + (size_t)M * F;                        // 8 MB
  unsigned short* Wht = Xl + (size_t)M * F;      // 2 layers x [2048][1024] = 8 MB
  unsigned short* Wlt = Wht + (size_t)2 * 2048 * 1024;             // 8 MB
  // total ws use ~81 MB

  k_prepAll<<<12416, 256, 0, stream>>>(A, x0, Wself, Wrel, brel, R,
                                       A1, A2, Xh, Xl, Wht, Wlt, xrr);

  // ---- layer 1 ----
  k_gemm_mfma<<<512, 512, 0, stream>>>(Xh, Xl, Wht, Wlt, xs, xrx, 1);
  k_agg<<<dim3(B, F / 128), 256, 0, stream>>>(A1, A2, xrx, P1h, P2h,
                                              xrr, xs, bself, x0, out,
                                              Xh, Xl, 0);
  // ---- layer 2 ----
  k_gemm_l2<<<1024, 512, 0, stream>>>(Xh, Xl,
                                      Wht + (size_t)2048 * 1024,
                                      Wlt + (size_t)2048 * 1024,
                                      xs, xrx, P1h, P2h);
  k_agg<<<dim3(B, F / 128), 256, 0, stream>>>(A1, A2, xrx, P1h, P2h,
                                              xrr + (size_t)RN * F, xs,
                                              bself + (size_t)F, out, out,
                                              nullptr, nullptr, 1);
}

// Round 20
// 158.644 us; speedup vs baseline: 1.0550x; 1.0205x over previous
//
#include <hip/hip_runtime.h>
#include <hip/hip_bf16.h>
#include <math.h>

#define B 64
#define O 64
#define F 1024
#define RN 16
#define RD 256
#define DEPTH 2
#define M (B*O)

typedef __attribute__((ext_vector_type(8))) _Float16 half8;
typedef __attribute__((ext_vector_type(4))) float f32x4;

#define RES_SCALE 2048.0f          // 2^11
#define RES_INV  (1.0f/2048.0f)

// ---------- fp16 helpers ----------
__device__ __forceinline__ unsigned short h2u(_Float16 h) {
  union { _Float16 h; unsigned short u; } c; c.h = h; return c.u;
}
__device__ __forceinline__ float u2f(unsigned short u) {
  union { _Float16 h; unsigned short u; } c; c.u = u; return (float)c.h;
}
__device__ __forceinline__ void split2(float x, unsigned short& h, unsigned short& l) {
  _Float16 hh = (_Float16)x;                       // RNE
  _Float16 ll = (_Float16)((x - (float)hh) * RES_SCALE);
  h = h2u(hh); l = h2u(ll);
}

__device__ __forceinline__ void gload_lds16(const unsigned short* g, void* l) {
  __builtin_amdgcn_global_load_lds(
      (const __attribute__((address_space(1))) unsigned int*)g,
      (__attribute__((address_space(3))) unsigned int*)l, 16, 0, 0);
}

// ------- merged prep: [0,4096) A-reduce; [4096,8192) splitX;
//         [8192,12288) splitW both layers; [12288,12416) xrr ------------------
__global__ __launch_bounds__(256) void k_prepAll(const float* __restrict__ A,
                                                 const float* __restrict__ X,
                                                 const float* __restrict__ Wself,
                                                 const float* __restrict__ Wrel,
                                                 const float* __restrict__ brel,
                                                 const float* __restrict__ R,
                                                 float* __restrict__ A1,
                                                 float* __restrict__ A2,
                                                 unsigned short* __restrict__ Xh,
                                                 unsigned short* __restrict__ Xl,
                                                 unsigned short* __restrict__ Wht,
                                                 unsigned short* __restrict__ Wlt,
                                                 float* __restrict__ xrr) {
  __shared__ float shm[32][33];
  const int t = threadIdx.x;
  const int bid = blockIdx.x;
  if (bid < 4096) {
    float* row = &shm[0][0];                 // 1056 floats > 1024 needed
    const int bo = bid;
    *reinterpret_cast<float4*>(&row[t * 4]) =
        *reinterpret_cast<const float4*>(&A[(size_t)bo * (O * RN) + t * 4]);
    __syncthreads();
    if (t < O) {
      float s = 0.f;
#pragma unroll
      for (int r = 0; r < RN; ++r) s += row[t * RN + r];
      A1[(size_t)bo * O + t] = s;
    } else if (t < O + RN) {
      const int r = t - O;
      float s = 0.f;
#pragma unroll
      for (int o2 = 0; o2 < O; ++o2) s += row[o2 * RN + r];
      A2[(size_t)bo * RN + r] = s;
    }
  } else if (bid < 8192) {
    const size_t i = ((size_t)(bid - 4096) * 256 + t) * 4;
    const float4 v = *reinterpret_cast<const float4*>(&X[i]);
    unsigned short h0, h1, h2, h3, l0, l1, l2, l3;
    split2(v.x, h0, l0); split2(v.y, h1, l1); split2(v.z, h2, l2); split2(v.w, h3, l3);
    uint2 hp, lp;
    hp.x = (unsigned)h0 | ((unsigned)h1 << 16); hp.y = (unsigned)h2 | ((unsigned)h3 << 16);
    lp.x = (unsigned)l0 | ((unsigned)l1 << 16); lp.y = (unsigned)l2 | ((unsigned)l3 << 16);
    *reinterpret_cast<uint2*>(&Xh[i]) = hp;
    *reinterpret_cast<uint2*>(&Xl[i]) = lp;
  } else if (bid < 12288) {
    const int wb = bid - 8192;
    const int z = wb >> 10;                  // layer*2 + sel
    const int rem = wb & 1023;
    const int k0 = (rem & 31) * 32, n0 = (rem >> 5) * 32;
    const int layer = z >> 1;
    const int sel = z & 1;
    const float* W = sel ? (Wrel + (size_t)layer * (F + RD) * F)
                         : (Wself + (size_t)layer * F * F);
    const size_t obase = (size_t)layer * 2048 * 1024 + (size_t)(sel ? 1024 : 0) * 1024;
    const int r = t >> 3, c4 = (t & 7) << 2;
    const float4 v = *reinterpret_cast<const float4*>(&W[(size_t)(k0 + r) * 1024 + n0 + c4]);
    shm[r][c4] = v.x; shm[r][c4 + 1] = v.y; shm[r][c4 + 2] = v.z; shm[r][c4 + 3] = v.w;
    __syncthreads();
    unsigned short h[4], l[4];
#pragma unroll
    for (int j = 0; j < 4; ++j) split2(shm[c4 + j][r], h[j], l[j]);
    uint2 hp, lp;
    hp.x = (unsigned)h[0] | ((unsigned)h[1] << 16); hp.y = (unsigned)h[2] | ((unsigned)h[3] << 16);
    lp.x = (unsigned)l[0] | ((unsigned)l[1] << 16); lp.y = (unsigned)l[2] | ((unsigned)l[3] << 16);
    const size_t o = obase + (size_t)(n0 + r) * 1024 + k0 + c4;
    *reinterpret_cast<uint2*>(&Wht[o]) = hp;
    *reinterpret_cast<uint2*>(&Wlt[o]) = lp;
  } else {
    const int r4 = bid - 12288;              // 0..127
    const int layer = r4 >> 6;
    const int idx = r4 & 63;
    const float* Wr = Wrel + (size_t)layer * (F + RD) * F + (size_t)F * F;
    const float* br = brel + (size_t)layer * F;
    const int r = idx >> 2;
    const int n = ((idx & 3) << 8) + t;
    float s = br[n];
    for (int k = 0; k < RD; ++k) s += R[r * RD + k] * Wr[(size_t)k * F + n];
    xrr[(size_t)layer * RN * F + (size_t)r * F + n] = s;
  }
}

// ---------------- staging + compute helpers (8-wave block, BK=64) ------------
__device__ __forceinline__ void stage_tiles8(const unsigned short* __restrict__ Asrc,
                                             const unsigned short* __restrict__ Bsrc,
                                             int bm, int bn, int k0,
                                             int w, int lane,
                                             char* Al, char* Bl) {
  const int srow = lane >> 3;
  const int sin = (lane & 7) << 4;
#pragma unroll
  for (int i = 0; i < 4; ++i) {
    const int c = (w << 2) + i;          // 0..31, wave-uniform
    const int cc = c & 15;
    const int row = (cc << 3) + srow;
    const int inrow = sin ^ ((row & 7) << 4);   // pre-swizzled SOURCE byte
    const unsigned short* src = (c < 16) ? Asrc : Bsrc;
    const int rbase = (c < 16) ? bm : bn;
    char* ldst = (c < 16) ? Al : Bl;
    gload_lds16(src + ((size_t)(rbase + row) << 10) + k0 + (inrow >> 1), ldst + (cc << 10));
  }
}

// per-wave 64x32 output: 4 m-frags x 2 n-frags; T5 setprio around MFMA cluster
__device__ __forceinline__ void compute_tile8(const char* Al, const char* Bl,
                                              int ar, int br, int kbyte,
                                              f32x4 (&acc)[4][2]) {
  __builtin_amdgcn_s_setprio(1);
#pragma unroll
  for (int kk = 0; kk < 2; ++kk) {
    half8 a[4], b[2];
#pragma unroll
    for (int m = 0; m < 4; ++m) {
      const int row = ar + m * 16;
      const int off = (row << 7) + (((kk << 6) + kbyte) ^ ((row & 7) << 4));
      a[m] = *reinterpret_cast<const half8*>(&Al[off]);
    }
#pragma unroll
    for (int n = 0; n < 2; ++n) {
      const int row = br + n * 16;
      const int off = (row << 7) + (((kk << 6) + kbyte) ^ ((row & 7) << 4));
      b[n] = *reinterpret_cast<const half8*>(&Bl[off]);
    }
#pragma unroll
    for (int m = 0; m < 4; ++m)
#pragma unroll
      for (int n = 0; n < 2; ++n)
        acc[m][n] = __builtin_amdgcn_mfma_f32_16x16x32_f16(a[m], b[n], acc[m][n], 0, 0, 0);
  }
  __builtin_amdgcn_s_setprio(0);
}

// 16-kt inner loop (K=1024), DOUBLE-BUFFERED single-barrier 2-phase (R16-proven):
// prologue stage(0->buf0); loop { stage(kt+1 -> buf^1); compute(buf); sync; }.
__device__ __forceinline__ void gemm_piece8(const unsigned short* __restrict__ Asrc,
                                            const unsigned short* __restrict__ Bsrc,
                                            int bm, int bn, int w, int lane,
                                            int ar, int br, int kbyte,
                                            char* Al0, char* Bl0,
                                            char* Al1, char* Bl1,
                                            f32x4 (&acc)[4][2]) {
  stage_tiles8(Asrc, Bsrc, bm, bn, 0, w, lane, Al0, Bl0);
  __syncthreads();
#pragma unroll
  for (int kt = 0; kt < 16; ++kt) {
    char* Ac = (kt & 1) ? Al1 : Al0;
    char* Bc = (kt & 1) ? Bl1 : Bl0;
    char* An = (kt & 1) ? Al0 : Al1;
    char* Bn = (kt & 1) ? Bl0 : Bl1;
    if (kt + 1 < 16)
      stage_tiles8(Asrc, Bsrc, bm, bn, (kt + 1) << 6, w, lane, An, Bn);
    compute_tile8(Ac, Bc, ar, br, kbyte, acc);
    __syncthreads();
  }
}

// ------- layer-1 fused MFMA GEMM ----------------------------------------------
// xrx half (bn>=1024): C = Xh@Wh + 2^-11*(Xh@Wl_st + Xl_st@Wh), K=3072 (48 steps)
// xs  half (bn< 1024): C = Xh@Wh + 2^-11*(Xl_st@Wh), K=2048 (32 steps) —
//   the dropped Xh@Wl term is ~1.4e-4, one-layer gain ~44 => ~6e-3 final, OK.
__global__ __launch_bounds__(512) void k_gemm_mfma(
    const unsigned short* __restrict__ Xh, const unsigned short* __restrict__ Xl,
    const unsigned short* __restrict__ Wht, const unsigned short* __restrict__ Wlt,
    float* __restrict__ xs, float* __restrict__ xrx) {
  __shared__ __align__(16) char Al0[128 * 128];
  __shared__ __align__(16) char Bl0[128 * 128];
  __shared__ __align__(16) char Al1[128 * 128];
  __shared__ __align__(16) char Bl1[128 * 128];
  const int t = threadIdx.x;
  const int lane = t & 63, w = t >> 6;
  const int bid = blockIdx.x;
  const int half = bid & 1;                 // 0 -> xrx (48 steps), 1 -> xs (32)
  int e = bid >> 1;
  e = (e & 7) * 32 + (e >> 3);               // XCD swizzle, bijective on 256
  const int bm = (e & 31) * 128;
  const int bn = (e >> 5) * 128 + (half ? 0 : 1024);
  const int wr = w >> 2, wc = w & 3;

  f32x4 accM[4][2], accR[4][2];
#pragma unroll
  for (int m = 0; m < 4; ++m)
#pragma unroll
    for (int n = 0; n < 2; ++n) { accM[m][n] = (f32x4)0.f; accR[m][n] = (f32x4)0.f; }

  const int ar = wr * 64 + (lane & 15);
  const int br = wc * 32 + (lane & 15);
  const int kbyte = (lane >> 4) << 4;

  gemm_piece8(Xh, Wht, bm, bn, w, lane, ar, br, kbyte, Al0, Bl0, Al1, Bl1, accM);
  if (half == 0)
    gemm_piece8(Xh, Wlt, bm, bn, w, lane, ar, br, kbyte, Al0, Bl0, Al1, Bl1, accR);
  gemm_piece8(Xl, Wht, bm, bn, w, lane, ar, br, kbyte, Al0, Bl0, Al1, Bl1, accR);

  float* dst = (bn < 1024) ? xs : xrx;
  const int coff = bn & 1023;
  const int lrow = (lane >> 4) << 2;
  const int lcol = lane & 15;
#pragma unroll
  for (int m = 0; m < 4; ++m)
#pragma unroll
    for (int n = 0; n < 2; ++n) {
      const int gr = bm + wr * 64 + m * 16 + lrow;
      const int gc = coff + wc * 32 + n * 16 + lcol;
#pragma unroll
      for (int i = 0; i < 4; ++i)
        dst[((size_t)(gr + i) << 10) + gc] = accM[m][n][i] + accR[m][n][i] * RES_INV;
    }
}

// ------- layer-2 GEMM: uniform 16-step blocks, 4 roles per tile-index ---------
// role 0: xs  = Xh@Wh (cols 0..1023)       role 1: xrx = Xh@Wh (cols 1024..)
// role 2: P1h = Xh@Wl_st (raw, fp16)       role 3: P2h = Xl_st@Wh (raw, fp16)
// consumer: xrx_eff = xrx + (P1+P2)*2^-11; xs needs no residual (last layer).
__global__ __launch_bounds__(512) void k_gemm_l2(
    const unsigned short* __restrict__ Xh, const unsigned short* __restrict__ Xl,
    const unsigned short* __restrict__ Wht, const unsigned short* __restrict__ Wlt,
    float* __restrict__ xs, float* __restrict__ xrx,
    unsigned short* __restrict__ P1h, unsigned short* __restrict__ P2h) {
  __shared__ __align__(16) char Al0[128 * 128];
  __shared__ __align__(16) char Bl0[128 * 128];
  __shared__ __align__(16) char Al1[128 * 128];
  __shared__ __align__(16) char Bl1[128 * 128];
  const int t = threadIdx.x;
  const int lane = t & 63, w = t >> 6;
  const int bid = blockIdx.x;
  const int role = bid & 3;
  int e = bid >> 2;
  e = (e & 7) * 32 + (e >> 3);               // XCD swizzle, bijective on 256
  const int bm = (e & 31) * 128;
  const int colblk = (e >> 5) * 128;
  const int bn = (role == 0) ? colblk : 1024 + colblk;
  const unsigned short* Asrc = (role == 3) ? Xl : Xh;
  const unsigned short* Bsrc = (role == 2) ? Wlt : Wht;
  const int wr = w >> 2, wc = w & 3;

  f32x4 acc[4][2];
#pragma unroll
  for (int m = 0; m < 4; ++m)
#pragma unroll
    for (int n = 0; n < 2; ++n) acc[m][n] = (f32x4)0.f;

  const int ar = wr * 64 + (lane & 15);
  const int br = wc * 32 + (lane & 15);
  const int kbyte = (lane >> 4) << 4;

  gemm_piece8(Asrc, Bsrc, bm, bn, w, lane, ar, br, kbyte, Al0, Bl0, Al1, Bl1, acc);

  const int lrow = (lane >> 4) << 2;
  const int lcol = lane & 15;
  if (role < 2) {
    float* dst = (role == 0) ? xs : xrx;
#pragma unroll
    for (int m = 0; m < 4; ++m)
#pragma unroll
      for (int n = 0; n < 2; ++n) {
        const int gr = bm + wr * 64 + m * 16 + lrow;
        const int gc = colblk + wc * 32 + n * 16 + lcol;
#pragma unroll
        for (int i = 0; i < 4; ++i)
          dst[((size_t)(gr + i) << 10) + gc] = acc[m][n][i];
      }
  } else {
    unsigned short* dst = (role == 2) ? P1h : P2h;
#pragma unroll
    for (int m = 0; m < 4; ++m)
#pragma unroll
      for (int n = 0; n < 2; ++n) {
        const int gr = bm + wr * 64 + m * 16 + lrow;
        const int gc = colblk + wc * 32 + n * 16 + lcol;
#pragma unroll
        for (int i = 0; i < 4; ++i)
          dst[((size_t)(gr + i) << 10) + gc] = h2u((_Float16)acc[m][n][i]);
      }
  }
}

// ------- out = tanh(xs + bself + A1[b]@xr_x[b] + A2[b]@xr_r + x_in) ----------
// use_p: xr_x = xrx + (P1h+P2h)*2^-11 (layer 2); else xr_x = xrx (layer 1).
// xin source: f32 xinF (layer 1) or fp16 split XhI/XlI (layer 2).
// xout: written only if non-null (layer 1 emits only the fp16 split XhO/XlO).
__global__ __launch_bounds__(256) void k_agg(const float* __restrict__ A1,
                                             const float* __restrict__ A2,
                                             const float* __restrict__ xrx,
                                             const unsigned short* __restrict__ P1h,
                                             const unsigned short* __restrict__ P2h,
                                             const float* __restrict__ xrr,
                                             const float* __restrict__ xs,
                                             const float* __restrict__ bias,
                                             const float* __restrict__ xinF,
                                             const unsigned short* __restrict__ XhI,
                                             const unsigned short* __restrict__ XlI,
                                             float* __restrict__ xout,
                                             unsigned short* __restrict__ XhO,
                                             unsigned short* __restrict__ XlO,
                                             int use_p) {
  __shared__ float A1s[O][O + 1];
  __shared__ float A2s[O][RN + 1];
  __shared__ float Xls[O][132];
  __shared__ float Rls[RN][132];
  const int b = blockIdx.x;
  const int f0 = blockIdx.y * 128;
  const int t = threadIdx.x;

#pragma unroll
  for (int i = 0; i < 4; ++i) {
    const int gi = i * 1024 + t * 4;
    const float4 v = *reinterpret_cast<const float4*>(&A1[(size_t)b * O * O + gi]);
    const int o = gi >> 6, c = gi & 63;
    A1s[o][c] = v.x; A1s[o][c + 1] = v.y; A1s[o][c + 2] = v.z; A1s[o][c + 3] = v.w;
  }
  {
    const int gi = t * 4;
    const float4 v = *reinterpret_cast<const float4*>(&A2[(size_t)b * O * RN + gi]);
    const int o = gi >> 4, c = gi & 15;
    A2s[o][c] = v.x; A2s[o][c + 1] = v.y; A2s[o][c + 2] = v.z; A2s[o][c + 3] = v.w;
  }
#pragma unroll
  for (int i = 0; i < 8; ++i) {
    const int gi = i * 1024 + t * 4;
    const int o2 = gi >> 7, c = gi & 127;
    const size_t pidx = ((size_t)(b * O + o2)) * F + f0 + c;
    float4 v = *reinterpret_cast<const float4*>(&xrx[pidx]);
    if (use_p) {
      const uint2 p1 = *reinterpret_cast<const uint2*>(&P1h[pidx]);
      const uint2 p2 = *reinterpret_cast<const uint2*>(&P2h[pidx]);
      v.x += (u2f((unsigned short)(p1.x & 0xffff)) + u2f((unsigned short)(p2.x & 0xffff))) * RES_INV;
      v.y += (u2f((unsigned short)(p1.x >> 16))    + u2f((unsigned short)(p2.x >> 16)))    * RES_INV;
      v.z += (u2f((unsigned short)(p1.y & 0xffff)) + u2f((unsigned short)(p2.y & 0xffff))) * RES_INV;
      v.w += (u2f((unsigned short)(p1.y >> 16))    + u2f((unsigned short)(p2.y >> 16)))    * RES_INV;
    }
    Xls[o2][c] = v.x; Xls[o2][c + 1] = v.y; Xls[o2][c + 2] = v.z; Xls[o2][c + 3] = v.w;
  }
#pragma unroll
  for (int i = 0; i < 2; ++i) {
    const int gi = i * 1024 + t * 4;
    const int r = gi >> 7, c = gi & 127;
    const float4 v = *reinterpret_cast<const float4*>(&xrr[(size_t)r * F + f0 + c]);
    Rls[r][c] = v.x; Rls[r][c + 1] = v.y; Rls[r][c + 2] = v.z; Rls[r][c + 3] = v.w;
  }
  __syncthreads();

  const int ob = (t >> 4) << 2;
  const int fc = (t & 15) << 2;
  float acc[4][8];
#pragma unroll
  for (int i = 0; i < 4; ++i)
#pragma unroll
    for (int j = 0; j < 8; ++j) acc[i][j] = 0.f;

#pragma unroll 4
  for (int o2 = 0; o2 < O; ++o2) {
    const float4 xa = *reinterpret_cast<const float4*>(&Xls[o2][fc]);
    const float4 xb = *reinterpret_cast<const float4*>(&Xls[o2][fc + 64]);
#pragma unroll
    for (int io = 0; io < 4; ++io) {
      const float a = A1s[ob + io][o2];
      acc[io][0] += a * xa.x; acc[io][1] += a * xa.y; acc[io][2] += a * xa.z; acc[io][3] += a * xa.w;
      acc[io][4] += a * xb.x; acc[io][5] += a * xb.y; acc[io][6] += a * xb.z; acc[io][7] += a * xb.w;
    }
  }
#pragma unroll
  for (int r = 0; r < RN; ++r) {
    const float4 xa = *reinterpret_cast<const float4*>(&Rls[r][fc]);
    const float4 xb = *reinterpret_cast<const float4*>(&Rls[r][fc + 64]);
#pragma unroll
    for (int io = 0; io < 4; ++io) {
      const float a = A2s[ob + io][r];
      acc[io][0] += a * xa.x; acc[io][1] += a * xa.y; acc[io][2] += a * xa.z; acc[io][3] += a * xa.w;
      acc[io][4] += a * xb.x; acc[io][5] += a * xb.y; acc[io][6] += a * xb.z; acc[io][7] += a * xb.w;
    }
  }

#pragma unroll
  for (int io = 0; io < 4; ++io) {
    const size_t base = ((size_t)(b * O + ob + io)) * F + f0;
#pragma unroll
    for (int seg = 0; seg < 2; ++seg) {
      const size_t idx = base + seg * 64 + fc;
      const float4 s = *reinterpret_cast<const float4*>(&xs[idx]);
      const float4 bv = *reinterpret_cast<const float4*>(&bias[f0 + seg * 64 + fc]);
      float4 xi;
      if (xinF) {
        xi = *reinterpret_cast<const float4*>(&xinF[idx]);
      } else {
        const uint2 xh = *reinterpret_cast<const uint2*>(&XhI[idx]);
        const uint2 xl = *reinterpret_cast<const uint2*>(&XlI[idx]);
        xi.x = u2f((unsigned short)(xh.x & 0xffff)) + u2f((unsigned short)(xl.x & 0xffff)) * RES_INV;
        xi.y = u2f((unsigned short)(xh.x >> 16))    + u2f((unsigned short)(xl.x >> 16))    * RES_INV;
        xi.z = u2f((unsigned short)(xh.y & 0xffff)) + u2f((unsigned short)(xl.y & 0xffff)) * RES_INV;
        xi.w = u2f((unsigned short)(xh.y >> 16))    + u2f((unsigned short)(xl.y >> 16))    * RES_INV;
      }
      float4 o;
      o.x = tanhf(acc[io][seg * 4 + 0] + s.x + bv.x + xi.x);
      o.y = tanhf(acc[io][seg * 4 + 1] + s.y + bv.y + xi.y);
      o.z = tanhf(acc[io][seg * 4 + 2] + s.z + bv.z + xi.z);
      o.w = tanhf(acc[io][seg * 4 + 3] + s.w + bv.w + xi.w);
      if (xout) *reinterpret_cast<float4*>(&xout[idx]) = o;
      if (XhO) {
        unsigned short h0, h1, h2, h3, l0, l1, l2, l3;
        split2(o.x, h0, l0); split2(o.y, h1, l1); split2(o.z, h2, l2); split2(o.w, h3, l3);
        uint2 hp, lp;
        hp.x = (unsigned)h0 | ((unsigned)h1 << 16); hp.y = (unsigned)h2 | ((unsigned)h3 << 16);
        lp.x = (unsigned)l0 | ((unsigned)l1 << 16); lp.y = (unsigned)l2 | ((unsigned)l3 << 16);
        *reinterpret_cast<uint2*>(&XhO[idx]) = hp;
        *reinterpret_cast<uint2*>(&XlO[idx]) = lp;
      }
    }
  }
}

extern "C" void kernel_launch(void* const* d_in, const int* in_sizes, int n_in,
                              void* d_out, int out_size, void* d_ws, size_t ws_size,
                              hipStream_t stream) {
  const float* x0    = (const float*)d_in[0];
  const float* A     = (const float*)d_in[1];
  const float* R     = (const float*)d_in[2];
  const float* Wself = (const float*)d_in[3];
  const float* bself = (const float*)d_in[4];
  const float* Wrel  = (const float*)d_in[5];
  const float* brel  = (const float*)d_in[6];
  float* out = (float*)d_out;

  float* ws  = (float*)d_ws;
  float* A1  = ws;                               // 1 MB
  float* A2  = A1 + (size_t)M * O;               // 0.25 MB
  float* xrr = A2 + (size_t)M * RN;              // 2 layers x RN x F
  float* xs  = xrr + (size_t)2 * RN * F;         // 16 MB
  float* xrx = xs + (size_t)M * F;               // 16 MB
  unsigned short* P1h = (unsigned short*)(xrx + (size_t)M * F);    // 8 MB
  unsigned short* P2h = P1h + (size_t)M * F;                       // 8 MB
  unsigned short* Xh  = P2h + (size_t)M * F;                       // 8 MB
  unsigned short* Xl  = Xh + (size_t)M * F;                        // 8 MB
  unsigned short* Wht = Xl + (size_t)M * F;      // 2 layers x [2048][1024] = 8 MB
  unsigned short* Wlt = Wht + (size_t)2 * 2048 * 1024;             // 8 MB
  // total ws use ~81 MB

  k_prepAll<<<12416, 256, 0, stream>>>(A, x0, Wself, Wrel, brel, R,
                                       A1, A2, Xh, Xl, Wht, Wlt, xrr);

  // ---- layer 1 ----
  k_gemm_mfma<<<512, 512, 0, stream>>>(Xh, Xl, Wht, Wlt, xs, xrx);
  // layer-1 agg: emits only the fp16 split of out (Xh/Xl); no f32 out write.
  k_agg<<<dim3(B, F / 128), 256, 0, stream>>>(A1, A2, xrx, P1h, P2h,
                                              xrr, xs, bself,
                                              x0, nullptr, nullptr,
                                              nullptr, Xh, Xl, 0);
  // ---- layer 2 ----
  k_gemm_l2<<<1024, 512, 0, stream>>>(Xh, Xl,
                                      Wht + (size_t)2048 * 1024,
                                      Wlt + (size_t)2048 * 1024,
                                      xs, xrx, P1h, P2h);
  // layer-2 agg: xin reconstructed from Xh/Xl; writes final f32 out.
  k_agg<<<dim3(B, F / 128), 256, 0, stream>>>(A1, A2, xrx, P1h, P2h,
                                              xrr + (size_t)RN * F, xs,
                                              bself + (size_t)F,
                                              nullptr, Xh, Xl,
                                              out, nullptr, nullptr, 1);
}